// Round 1
// baseline (6190.641 us; speedup 1.0000x reference)
//
#include <hip/hip_runtime.h>
#include <hip/hip_cooperative_groups.h>

// Tree-GRU encoder (EncoderRNN): bottom-up (children-sum) + top-down (parent) GRU
// passes. Key facts exploited:
//  - batch rows are independent; only the N-split of the 1536-wide gate GEMM
//    couples blocks -> one grid sync per step (cooperative kernel).
//  - "sum of children" einsum == running scatter Hsum[b, parent] += h_new.
//  - tolerance is ~2% of max -> bf16 MFMA internal math is allowed.
//
// ws layout (bytes):            need ~107 MB total
//   [0)              Hsum bf16  [B][L][H]   33,554,432  (zeroed every call)
//   [33.5M)          Htd  bf16  [B][L][H]   33,554,432  (read-before-write only at masked root)
//   [67.1M)          emb  bf16  [L][B][D]   33,554,432
//   [100.7M)         WT   bf16  4x[1536][512] 6,291,456 (dtWx,dtUh,tdWx,tdUh transposed)

#define NL 256
#define NB 128
#define ND 512
#define NH 512

typedef short short8 __attribute__((ext_vector_type(8)));
typedef float f32x4 __attribute__((ext_vector_type(4)));

__device__ __forceinline__ float bf2f(unsigned short u) {
  union { unsigned int i; float f; } c; c.i = ((unsigned int)u) << 16; return c.f;
}
__device__ __forceinline__ unsigned short f2bf(float f) {
  union { float f; unsigned int i; } c; c.f = f;
  return (unsigned short)((c.i + 0x7FFFu + ((c.i >> 16) & 1u)) >> 16);  // RNE
}

// ---- prep: zero Hsum, emb f32 -> bf16 ----
__global__ void prep_misc(const float* __restrict__ emb,
                          unsigned int* __restrict__ embbf_w,
                          unsigned int* __restrict__ hsum_w) {
  int i = blockIdx.x * blockDim.x + threadIdx.x;
  int stride = gridDim.x * blockDim.x;
  const int nzero = NB * NL * NH / 2;   // uint words over bf16 Hsum
  for (int j = i; j < nzero; j += stride) hsum_w[j] = 0u;
  const int nemb2 = NL * NB * ND / 2;
  const float2* e2 = (const float2*)emb;
  for (int j = i; j < nemb2; j += stride) {
    float2 v = e2[j];
    embbf_w[j] = (unsigned int)f2bf(v.x) | ((unsigned int)f2bf(v.y) << 16);
  }
}

// ---- prep: weight [512][1536] f32 -> transposed [1536][512] bf16 (LDS tile transpose) ----
__global__ void prep_wt(const float* __restrict__ w, unsigned short* __restrict__ wt) {
  __shared__ float t[32][33];
  int n0 = blockIdx.x * 32, k0 = blockIdx.y * 32;
  int tx = threadIdx.x & 31, ty = threadIdx.x >> 5;   // 256 thr: ty 0..7
  #pragma unroll
  for (int i = 0; i < 4; ++i)
    t[ty + 8 * i][tx] = w[(size_t)(k0 + ty + 8 * i) * 1536 + n0 + tx];
  __syncthreads();
  #pragma unroll
  for (int i = 0; i < 4; ++i)
    wt[(size_t)(n0 + ty + 8 * i) * 512 + k0 + tx] = f2bf(t[tx][ty + 8 * i]);
}

// ---- main persistent cooperative kernel ----
// grid = 128 blocks x 256 thr (4 waves). block: pass(2) x rowgroup(2, 64 rows) x colgroup(32, 16 h-cols)
// wave w: rows [rg*64 + w*16, +16), cols [cg*16, +16). Weights for this block's 3 gate strips
// (Wx and Uh, 48+48 cols x 512 K, bf16) live in LDS for all 256 steps (98,304 B).
__launch_bounds__(256, 1)
__global__ void tree_gru(const int* __restrict__ indexes,
                         const int* __restrict__ td_node,
                         const int* __restrict__ td_pidx,
                         const float* __restrict__ td_pval,
                         const int* __restrict__ root_index,
                         const float* __restrict__ dt_b,
                         const float* __restrict__ td_b,
                         const unsigned short* __restrict__ embbf,
                         unsigned short* __restrict__ hsum,
                         unsigned short* __restrict__ htd,
                         const unsigned short* __restrict__ wt,
                         float* __restrict__ out) {
  extern __shared__ unsigned char lds[];
  const int tid = threadIdx.x;
  const int bi  = blockIdx.x;
  const int pass = bi >> 6;         // 0 = DT bottom-up, 1 = TD top-down
  const int rg   = (bi >> 5) & 1;
  const int cg   = bi & 31;
  const int w  = tid >> 6, l = tid & 63;
  const int lm = l & 15, kg = l >> 4;
  const int rowbase = rg * 64 + w * 16;
  const int col = cg * 16 + lm;     // h-column 0..511

  // stage weight slices: LDS layout [mat(Wx,Uh)][gate(r,z,n)][n16][k512] bf16,
  // XOR-swizzle low k-bytes by n to break the 1KB-stride 16-way bank conflict.
  for (int idx = tid; idx < 6144; idx += 256) {
    int k8  = idx & 63;
    int n   = (idx >> 6) & 15;
    int g   = (idx >> 10) % 3;
    int mat = idx / 3072;
    const unsigned short* src = wt + (size_t)(pass * 2 + mat) * (1536 * 512)
                                   + (size_t)(g * 512 + cg * 16 + n) * 512 + k8 * 8;
    short8 v = *(const short8*)src;
    int off = ((mat * 3 + g) * 16 + n) * 1024 + ((k8 * 16) ^ ((n & 7) << 4));
    *(short8*)(lds + off) = v;
  }
  __syncthreads();

  const float* bias = pass ? td_b : dt_b;
  const float br = bias[col], bz = bias[512 + col], bn = bias[1024 + col];

  const int bA  = rowbase + lm;        // this lane's A-operand batch row
  const int swz = (lm & 7) << 4;
  const int base_wr = (0 * 16 + lm) * 1024;
  const int base_wz = (1 * 16 + lm) * 1024;
  const int base_wn = (2 * 16 + lm) * 1024;
  const int base_ur = (3 * 16 + lm) * 1024;
  const int base_uz = (4 * 16 + lm) * 1024;
  const int base_un = (5 * 16 + lm) * 1024;

  cooperative_groups::grid_group grid = cooperative_groups::this_grid();

  for (int s = 0; s < NL; ++s) {
    const unsigned short *aH, *aX;
    int hval;
    if (pass == 0) {
      int node = indexes[s * NB + bA];
      aH = hsum + ((size_t)bA * NL + node) * NH;      // children-sum row
      aX = embbf + ((size_t)node * NB + bA) * ND;     // emb[node, b, :]
      hval = 1;
    } else {
      int node = td_node[s * NB + bA];
      int pidx = td_pidx[s * NB + bA];
      hval = (td_pval[s * NB + bA] != 0.f);           // root -> zero h_prev
      aH = htd + ((size_t)bA * NL + pidx) * NH;
      aX = embbf + ((size_t)node * NB + bA) * ND;
    }
    f32x4 aR  = {0.f, 0.f, 0.f, 0.f}, aZ  = {0.f, 0.f, 0.f, 0.f};
    f32x4 aXN = {0.f, 0.f, 0.f, 0.f}, aHN = {0.f, 0.f, 0.f, 0.f};
    #pragma unroll 4
    for (int kk = 0; kk < 16; ++kk) {
      const int ke = kk * 32 + kg * 8;
      const int kb = (kk * 64 + kg * 16) ^ swz;
      short8 ax = *(const short8*)(aX + ke);
      short8 ah = {0, 0, 0, 0, 0, 0, 0, 0};
      if (hval) ah = *(const short8*)(aH + ke);
      short8 bwr = *(const short8*)(lds + base_wr + kb);
      short8 bwz = *(const short8*)(lds + base_wz + kb);
      short8 bwn = *(const short8*)(lds + base_wn + kb);
      short8 bur = *(const short8*)(lds + base_ur + kb);
      short8 buz = *(const short8*)(lds + base_uz + kb);
      short8 bun = *(const short8*)(lds + base_un + kb);
      // r/z: x-side and h-side accumulate into the same pre-activation.
      // n: keep xn and hn separate (n = tanh(xn + r*hn)).
      aR  = __builtin_amdgcn_mfma_f32_16x16x32_bf16(ax, bwr, aR, 0, 0, 0);
      aZ  = __builtin_amdgcn_mfma_f32_16x16x32_bf16(ax, bwz, aZ, 0, 0, 0);
      aXN = __builtin_amdgcn_mfma_f32_16x16x32_bf16(ax, bwn, aXN, 0, 0, 0);
      aR  = __builtin_amdgcn_mfma_f32_16x16x32_bf16(ah, bur, aR, 0, 0, 0);
      aZ  = __builtin_amdgcn_mfma_f32_16x16x32_bf16(ah, buz, aZ, 0, 0, 0);
      aHN = __builtin_amdgcn_mfma_f32_16x16x32_bf16(ah, bun, aHN, 0, 0, 0);
    }
    // epilogue: C/D frag layout row=(l>>4)*4+q, col=l&15
    #pragma unroll
    for (int q = 0; q < 4; ++q) {
      int bO = rowbase + kg * 4 + q;
      float hprev; int node; int do_scat = 0; int parent = 0;
      if (pass == 0) {
        node = indexes[s * NB + bO];
        hprev = bf2f(hsum[((size_t)bO * NL + node) * NH + col]);
        float pv = td_pval[node * NB + bO];
        parent = td_pidx[node * NB + bO];
        do_scat = (pv != 0.f);
      } else {
        node = td_node[s * NB + bO];
        int pidx = td_pidx[s * NB + bO];
        float pv = td_pval[s * NB + bO];
        hprev = (pv != 0.f) ? bf2f(htd[((size_t)bO * NL + pidx) * NH + col]) : 0.f;
      }
      float r = 1.f / (1.f + __expf(-(aR[q] + br)));
      float z = 1.f / (1.f + __expf(-(aZ[q] + bz)));
      float e2 = __expf(2.f * (aXN[q] + bn + r * aHN[q]));
      float nn = (e2 - 1.f) / (e2 + 1.f);              // tanh
      float h = (1.f - z) * nn + z * hprev;
      out[((size_t)bO * NL + node) * 1024 + pass * 512 + col] = h;
      if (pass == 0) {
        if (do_scat) {  // Hsum[b, parent] += h   (this (b,col) owned by exactly this lane)
          size_t po = ((size_t)bO * NL + parent) * NH + col;
          hsum[po] = f2bf(bf2f(hsum[po]) + h);
        }
      } else {
        htd[((size_t)bO * NL + node) * NH + col] = f2bf(h);
      }
    }
    grid.sync();
  }

  // output_t: root hidden concat, one block per batch row (grid == 128 == B)
  {
    int b = bi;
    int root = root_index[b];
    for (int c = tid; c < 1024; c += 256) {
      out[(size_t)NB * NL * 1024 + (size_t)b * 1024 + c] =
          out[((size_t)b * NL + root) * 1024 + c];
    }
  }
}

extern "C" void kernel_launch(void* const* d_in, const int* in_sizes, int n_in,
                              void* d_out, int out_size, void* d_ws, size_t ws_size,
                              hipStream_t stream) {
  (void)in_sizes; (void)n_in; (void)out_size; (void)ws_size;
  const float* emb      = (const float*)d_in[0];
  const int*   indexes  = (const int*)d_in[1];
  // d_in[2] = child_mask: unused (equivalent to parent-pointer scatter)
  const int*   td_node  = (const int*)d_in[3];
  const int*   td_pidx  = (const int*)d_in[4];
  const float* td_pval  = (const float*)d_in[5];
  const int*   root_idx = (const int*)d_in[6];
  const float* dt_Wx    = (const float*)d_in[7];
  const float* dt_Uh    = (const float*)d_in[8];
  const float* dt_b     = (const float*)d_in[9];
  const float* td_Wx    = (const float*)d_in[10];
  const float* td_Uh    = (const float*)d_in[11];
  const float* td_b     = (const float*)d_in[12];
  float* out = (float*)d_out;

  unsigned short* hsum  = (unsigned short*)d_ws;
  unsigned short* htd   = hsum + (size_t)NB * NL * NH;
  unsigned short* embbf = htd + (size_t)NB * NL * NH;
  unsigned short* wt    = embbf + (size_t)NL * NB * ND;

  prep_misc<<<dim3(1024), dim3(256), 0, stream>>>(emb, (unsigned int*)embbf,
                                                  (unsigned int*)hsum);
  dim3 tg(48, 16);
  prep_wt<<<tg, dim3(256), 0, stream>>>(dt_Wx, wt);
  prep_wt<<<tg, dim3(256), 0, stream>>>(dt_Uh, wt + (size_t)1536 * 512);
  prep_wt<<<tg, dim3(256), 0, stream>>>(td_Wx, wt + (size_t)2 * 1536 * 512);
  prep_wt<<<tg, dim3(256), 0, stream>>>(td_Uh, wt + (size_t)3 * 1536 * 512);

  (void)hipFuncSetAttribute((const void*)tree_gru,
                            hipFuncAttributeMaxDynamicSharedMemorySize, 98304);

  void* args[] = {
    (void*)&indexes, (void*)&td_node, (void*)&td_pidx, (void*)&td_pval, (void*)&root_idx,
    (void*)&dt_b, (void*)&td_b, (void*)&embbf, (void*)&hsum, (void*)&htd, (void*)&wt,
    (void*)&out
  };
  (void)hipLaunchCooperativeKernel((const void*)tree_gru, dim3(128), dim3(256),
                                   args, 98304u, stream);
}

// Round 2
// 3181.316 us; speedup vs baseline: 1.9459x; 1.9459x over previous
//
#include <hip/hip_runtime.h>
#include <hip/hip_cooperative_groups.h>

// Tree-GRU encoder, level-scheduled.
//  - Nodes at the same tree depth are independent -> phases = max tree height+1
//    (~21 for random recursive trees) instead of 256 serial steps.
//  - DT (bottom-up) phase p processes depth Dmax-p; "sum of children" is a
//    running scatter: atomicAdd(f32) into hsum[b][parent] (siblings in the same
//    level may share a parent -> atomics required).
//  - TD (top-down) phase p processes depth p; hidden state lives directly in
//    d_out (f32, cols 512..1023), no separate buffer.
//  - Weights stay LDS-resident per (pass, colgroup) block for all phases.
//
// ws layout:
//   [0)        hsum  f32 [B][L][H]        67,108,864 B (zeroed each call)
//   [67.1M)    wt    bf16 4x[1536][512]    6,291,456 B
//   [73.4M)    sched i32 [32768]             131,072 B  ((b<<8)|node, bucketed by depth)
//   [73.5M)    meta  i32 [513]  ([0]=Dmax, [1+d]=off, [257+d]=cnt)

#define NL 256
#define NB 128
#define ND 512
#define NH 512

typedef short short8 __attribute__((ext_vector_type(8)));
typedef float f32x4 __attribute__((ext_vector_type(4)));

__device__ __forceinline__ unsigned short f2bf(float f) {
  union { float f; unsigned int i; } c; c.f = f;
  return (unsigned short)((c.i + 0x7FFFu + ((c.i >> 16) & 1u)) >> 16);  // RNE
}

// pack 8 f32 -> 8 bf16 via v_cvt_pk_bf16_f32 (RNE), element 0 -> word0.lo
__device__ __forceinline__ short8 pk_bf16(f32x4 a, f32x4 b) {
  union { unsigned int u[4]; short8 s; } r;
  asm("v_cvt_pk_bf16_f32 %0, %1, %2" : "=v"(r.u[0]) : "v"(a[0]), "v"(a[1]));
  asm("v_cvt_pk_bf16_f32 %0, %1, %2" : "=v"(r.u[1]) : "v"(a[2]), "v"(a[3]));
  asm("v_cvt_pk_bf16_f32 %0, %1, %2" : "=v"(r.u[2]) : "v"(b[0]), "v"(b[1]));
  asm("v_cvt_pk_bf16_f32 %0, %1, %2" : "=v"(r.u[3]) : "v"(b[2]), "v"(b[3]));
  return r.s;
}

// ---- prep: zero hsum (f32) ----
__global__ void prep_zero(f32x4* __restrict__ hsum4) {
  int i = blockIdx.x * blockDim.x + threadIdx.x;
  int stride = gridDim.x * blockDim.x;
  const int n = NB * NL * NH / 4;
  f32x4 z = {0.f, 0.f, 0.f, 0.f};
  for (int j = i; j < n; j += stride) hsum4[j] = z;
}

// ---- prep: weight [512][1536] f32 -> transposed [1536][512] bf16 ----
__global__ void prep_wt(const float* __restrict__ w, unsigned short* __restrict__ wt) {
  __shared__ float t[32][33];
  int n0 = blockIdx.x * 32, k0 = blockIdx.y * 32;
  int tx = threadIdx.x & 31, ty = threadIdx.x >> 5;
  #pragma unroll
  for (int i = 0; i < 4; ++i)
    t[ty + 8 * i][tx] = w[(size_t)(k0 + ty + 8 * i) * 1536 + n0 + tx];
  __syncthreads();
  #pragma unroll
  for (int i = 0; i < 4; ++i)
    wt[(size_t)(n0 + ty + 8 * i) * 512 + k0 + tx] = f2bf(t[tx][ty + 8 * i]);
}

// ---- prep: depths + level-bucketed schedule (1 block, 128 threads) ----
__global__ void prep_sched(const int* __restrict__ td_pidx,
                           const float* __restrict__ td_pval,
                           int* __restrict__ sched, int* __restrict__ meta) {
  __shared__ unsigned char dep[NB][NL];
  __shared__ int cnt[256], cur[256], off[257];
  __shared__ int dmax;
  const int b = threadIdx.x;
  for (int d = b; d < 256; d += NB) { cnt[d] = 0; cur[d] = 0; }
  if (b == 0) dmax = 0;
  __syncthreads();
  int lmax = 0;
  for (int i = 0; i < NL; ++i) {
    float pv = td_pval[i * NB + b];
    int pi = td_pidx[i * NB + b];
    int d = (pv != 0.f) ? (int)dep[b][pi] + 1 : 0;   // head[i] < i: dep[b][pi] ready
    dep[b][i] = (unsigned char)d;
    atomicAdd(&cnt[d], 1);
    lmax = max(lmax, d);
  }
  atomicMax(&dmax, lmax);
  __syncthreads();
  if (b == 0) {
    int s = 0;
    for (int d = 0; d < 256; ++d) { off[d] = s; s += cnt[d]; }
    off[256] = s;
  }
  __syncthreads();
  for (int i = 0; i < NL; ++i) {
    int d = dep[b][i];
    int pos = off[d] + atomicAdd(&cur[d], 1);
    sched[pos] = (b << 8) | i;
  }
  if (b == 0) meta[0] = dmax;
  for (int d = b; d < 256; d += NB) { meta[1 + d] = off[d]; meta[257 + d] = cnt[d]; }
}

// ---- main persistent cooperative kernel ----
// grid = 256 blocks x 256 thr. block: pass(2) x replica(4) x colgroup(32 x 16 cols).
// Weight slices for this (pass, cg) live in LDS (98,304 B) for all phases.
// Per phase: DT handles depth Dmax-p, TD handles depth p; tiles of 16 rows
// distributed over 16 wave-slots (4 replicas x 4 waves) per (pass,cg).
__launch_bounds__(256, 1)
__global__ void tree_gru(const int* __restrict__ td_pidx,
                         const float* __restrict__ td_pval,
                         const int* __restrict__ root_index,
                         const float* __restrict__ dt_b,
                         const float* __restrict__ td_b,
                         const float* __restrict__ emb,
                         float* __restrict__ hsum,
                         const unsigned short* __restrict__ wt,
                         const int* __restrict__ sched,
                         const int* __restrict__ meta,
                         float* __restrict__ out) {
  extern __shared__ unsigned char lds[];
  const int tid = threadIdx.x;
  const int bi  = blockIdx.x;
  const int pass = bi >> 7;          // 0 = DT bottom-up, 1 = TD top-down
  const int rep  = (bi >> 5) & 3;
  const int cg   = bi & 31;
  const int w  = tid >> 6, l = tid & 63;
  const int lm = l & 15, kg = l >> 4;
  const int col = cg * 16 + lm;
  const int slot = rep * 4 + w;      // 0..15 tile slot within (pass,cg)

  // stage weight slices: [mat(Wx,Uh)][gate(r,z,n)][n16][k512] bf16, XOR-swizzled
  for (int idx = tid; idx < 6144; idx += 256) {
    int k8  = idx & 63;
    int n   = (idx >> 6) & 15;
    int g   = (idx >> 10) % 3;
    int mat = idx / 3072;
    const unsigned short* src = wt + (size_t)(pass * 2 + mat) * (1536 * 512)
                                   + (size_t)(g * 512 + cg * 16 + n) * 512 + k8 * 8;
    short8 v = *(const short8*)src;
    int off = ((mat * 3 + g) * 16 + n) * 1024 + ((k8 * 16) ^ ((n & 7) << 4));
    *(short8*)(lds + off) = v;
  }
  __syncthreads();

  const float* bias = pass ? td_b : dt_b;
  const float br = bias[col], bz = bias[NH + col], bn = bias[2 * NH + col];
  const int swz = (lm & 7) << 4;
  const int base_wr = (0 * 16 + lm) * 1024;
  const int base_wz = (1 * 16 + lm) * 1024;
  const int base_wn = (2 * 16 + lm) * 1024;
  const int base_ur = (3 * 16 + lm) * 1024;
  const int base_uz = (4 * 16 + lm) * 1024;
  const int base_un = (5 * 16 + lm) * 1024;

  cooperative_groups::grid_group grid = cooperative_groups::this_grid();
  const int Dmax = meta[0];

  for (int p = 0; p <= Dmax; ++p) {
    const int d = pass ? p : (Dmax - p);
    const int off_d = meta[1 + d];
    const int cnt_d = meta[257 + d];
    const int T = (cnt_d + 15) >> 4;
    for (int t = slot; t < T; t += 16) {
      const int sbase = off_d + t * 16;
      const int rows = min(16, cnt_d - t * 16);
      // A-operand row for this lane (duplicates clamped; writes masked later)
      const int e = sched[sbase + min(lm, rows - 1)];
      const int ab = e >> 8, anode = e & 255;
      const float* aX = emb + ((size_t)anode * NB + ab) * ND;
      const float* aH;
      int hval;
      if (pass == 0) {
        aH = hsum + ((size_t)ab * NL + anode) * NH;   // children sum (f32)
        hval = 1;
      } else {
        int pidx = td_pidx[anode * NB + ab];
        hval = (td_pval[anode * NB + ab] != 0.f);
        aH = out + ((size_t)ab * NL + pidx) * 1024 + 512;  // parent TD hidden
      }
      f32x4 aR  = {0.f,0.f,0.f,0.f}, aZ  = {0.f,0.f,0.f,0.f};
      f32x4 aXN = {0.f,0.f,0.f,0.f}, aHN = {0.f,0.f,0.f,0.f};
      #pragma unroll 4
      for (int kk = 0; kk < 16; ++kk) {
        const int ke = kk * 32 + kg * 8;
        const int kb = (kk * 64 + kg * 16) ^ swz;
        f32x4 x0 = *(const f32x4*)(aX + ke);
        f32x4 x1 = *(const f32x4*)(aX + ke + 4);
        short8 ax = pk_bf16(x0, x1);
        f32x4 h0 = {0.f,0.f,0.f,0.f}, h1 = {0.f,0.f,0.f,0.f};
        if (hval) { h0 = *(const f32x4*)(aH + ke); h1 = *(const f32x4*)(aH + ke + 4); }
        short8 ah = pk_bf16(h0, h1);
        short8 bwr = *(const short8*)(lds + base_wr + kb);
        short8 bwz = *(const short8*)(lds + base_wz + kb);
        short8 bwn = *(const short8*)(lds + base_wn + kb);
        short8 bur = *(const short8*)(lds + base_ur + kb);
        short8 buz = *(const short8*)(lds + base_uz + kb);
        short8 bun = *(const short8*)(lds + base_un + kb);
        aR  = __builtin_amdgcn_mfma_f32_16x16x32_bf16(ax, bwr, aR, 0, 0, 0);
        aZ  = __builtin_amdgcn_mfma_f32_16x16x32_bf16(ax, bwz, aZ, 0, 0, 0);
        aXN = __builtin_amdgcn_mfma_f32_16x16x32_bf16(ax, bwn, aXN, 0, 0, 0);
        aR  = __builtin_amdgcn_mfma_f32_16x16x32_bf16(ah, bur, aR, 0, 0, 0);
        aZ  = __builtin_amdgcn_mfma_f32_16x16x32_bf16(ah, buz, aZ, 0, 0, 0);
        aHN = __builtin_amdgcn_mfma_f32_16x16x32_bf16(ah, bun, aHN, 0, 0, 0);
      }
      // epilogue: C/D frag row=(kg*4+q), col=lm
      #pragma unroll
      for (int q = 0; q < 4; ++q) {
        const int r = kg * 4 + q;
        if (r >= rows) continue;
        const int eo = sched[sbase + r];
        const int bO = eo >> 8, node = eo & 255;
        float hprev;
        if (pass == 0) {
          hprev = hsum[((size_t)bO * NL + node) * NH + col];
        } else {
          int pidx = td_pidx[node * NB + bO];
          float pv = td_pval[node * NB + bO];
          hprev = (pv != 0.f) ? out[((size_t)bO * NL + pidx) * 1024 + 512 + col] : 0.f;
        }
        float rr = 1.f / (1.f + __expf(-(aR[q] + br)));
        float zz = 1.f / (1.f + __expf(-(aZ[q] + bz)));
        float e2 = __expf(2.f * (aXN[q] + bn + rr * aHN[q]));
        float nn = (e2 - 1.f) / (e2 + 1.f);             // tanh
        float h = (1.f - zz) * nn + zz * hprev;
        out[((size_t)bO * NL + node) * 1024 + pass * 512 + col] = h;
        if (pass == 0) {
          float pv = td_pval[node * NB + bO];
          if (pv != 0.f) {
            int parent = td_pidx[node * NB + bO];
            atomicAdd(&hsum[((size_t)bO * NL + parent) * NH + col], h);
          }
        }
      }
    }
    grid.sync();
  }

  // output_t: root hidden concat
  if (bi < NB) {
    int b = bi, root = root_index[b];
    for (int c = tid; c < 1024; c += 256)
      out[(size_t)NB * NL * 1024 + (size_t)b * 1024 + c] =
          out[((size_t)b * NL + root) * 1024 + c];
  }
}

extern "C" void kernel_launch(void* const* d_in, const int* in_sizes, int n_in,
                              void* d_out, int out_size, void* d_ws, size_t ws_size,
                              hipStream_t stream) {
  (void)in_sizes; (void)n_in; (void)out_size; (void)ws_size;
  const float* emb      = (const float*)d_in[0];
  // d_in[1] indexes, d_in[2] child_mask, d_in[3] td_node: unused (level schedule)
  const int*   td_pidx  = (const int*)d_in[4];
  const float* td_pval  = (const float*)d_in[5];
  const int*   root_idx = (const int*)d_in[6];
  const float* dt_Wx    = (const float*)d_in[7];
  const float* dt_Uh    = (const float*)d_in[8];
  const float* dt_b     = (const float*)d_in[9];
  const float* td_Wx    = (const float*)d_in[10];
  const float* td_Uh    = (const float*)d_in[11];
  const float* td_b     = (const float*)d_in[12];
  float* out = (float*)d_out;

  float* hsum = (float*)d_ws;
  unsigned short* wt = (unsigned short*)(hsum + (size_t)NB * NL * NH);
  int* sched = (int*)(wt + (size_t)4 * 1536 * 512);
  int* meta  = sched + NB * NL;

  prep_zero<<<dim3(1024), dim3(256), 0, stream>>>((f32x4*)hsum);
  dim3 tg(48, 16);
  prep_wt<<<tg, dim3(256), 0, stream>>>(dt_Wx, wt);
  prep_wt<<<tg, dim3(256), 0, stream>>>(dt_Uh, wt + (size_t)1536 * 512);
  prep_wt<<<tg, dim3(256), 0, stream>>>(td_Wx, wt + (size_t)2 * 1536 * 512);
  prep_wt<<<tg, dim3(256), 0, stream>>>(td_Uh, wt + (size_t)3 * 1536 * 512);
  prep_sched<<<dim3(1), dim3(NB), 0, stream>>>(td_pidx, td_pval, sched, meta);

  (void)hipFuncSetAttribute((const void*)tree_gru,
                            hipFuncAttributeMaxDynamicSharedMemorySize, 98304);

  void* args[] = {
    (void*)&td_pidx, (void*)&td_pval, (void*)&root_idx,
    (void*)&dt_b, (void*)&td_b, (void*)&emb, (void*)&hsum, (void*)&wt,
    (void*)&sched, (void*)&meta, (void*)&out
  };
  (void)hipLaunchCooperativeKernel((const void*)tree_gru, dim3(256), dim3(256),
                                   args, 98304u, stream);
}

// Round 3
// 2130.094 us; speedup vs baseline: 2.9063x; 1.4935x over previous
//
#include <hip/hip_runtime.h>
#include <hip/hip_cooperative_groups.h>

// Tree-GRU encoder, level-scheduled with COMPACT level-ordered bf16 state.
//  - prep_sched computes depth of every (b,node), buckets into levels, assigns
//    each node a global slot g (level-major). pslot[g] = parent's slot (-1 root).
//  - Xc[g][512] bf16: emb rows pre-gathered in slot order (contiguous per level).
//  - Hdt[g][512] bf16: children-sum, accumulated by child epilogues via
//    global_atomic_pk_add_bf16 at the parent's slot. Pre-zeroed (memset).
//  - Htd[g][512] bf16: TD hidden at own slot; children gather parent rows.
//  - Cooperative kernel: 256 blocks (1/CU), weights LDS-resident, ONE grid.sync
//    per level. DT processes depth Dmax-p, TD depth p, concurrently.
//
// ws layout (107.3 MB, same proven footprint as round 1):
//   wt    bf16 4x[1536][512]   6,291,456 B
//   Xc    bf16 [32768][512]   33,554,432 B
//   Hdt   bf16 [32768][512]   33,554,432 B   (memset 0 each call)
//   Htd   bf16 [32768][512]   33,554,432 B
//   sched i32  [32768], meta i32 [513], gidx i32 [32768], pslot i32 [32768]

#define NL 256
#define NB 128
#define NH 512
#define NG (NB * NL)

typedef short short8 __attribute__((ext_vector_type(8)));
typedef float f32x4 __attribute__((ext_vector_type(4)));

__device__ __forceinline__ float bf2f(unsigned short u) {
  union { unsigned int i; float f; } c; c.i = ((unsigned int)u) << 16; return c.f;
}
__device__ __forceinline__ unsigned short f2bf(float f) {
  union { float f; unsigned int i; } c; c.f = f;
  return (unsigned short)((c.i + 0x7FFFu + ((c.i >> 16) & 1u)) >> 16);  // RNE
}
__device__ __forceinline__ short8 pk_bf16(f32x4 a, f32x4 b) {
  union { unsigned int u[4]; short8 s; } r;
  asm("v_cvt_pk_bf16_f32 %0, %1, %2" : "=v"(r.u[0]) : "v"(a[0]), "v"(a[1]));
  asm("v_cvt_pk_bf16_f32 %0, %1, %2" : "=v"(r.u[1]) : "v"(a[2]), "v"(a[3]));
  asm("v_cvt_pk_bf16_f32 %0, %1, %2" : "=v"(r.u[2]) : "v"(b[0]), "v"(b[1]));
  asm("v_cvt_pk_bf16_f32 %0, %1, %2" : "=v"(r.u[3]) : "v"(b[2]), "v"(b[3]));
  return r.s;
}
__device__ __forceinline__ void atom_pk_bf16(unsigned short* p, unsigned int ud) {
  asm volatile("global_atomic_pk_add_bf16 %0, %1, off" :: "v"((void*)p), "v"(ud) : "memory");
}

// ---- prep: weight [512][1536] f32 -> transposed [1536][512] bf16 ----
__global__ void prep_wt(const float* __restrict__ w, unsigned short* __restrict__ wt) {
  __shared__ float t[32][33];
  int n0 = blockIdx.x * 32, k0 = blockIdx.y * 32;
  int tx = threadIdx.x & 31, ty = threadIdx.x >> 5;
  #pragma unroll
  for (int i = 0; i < 4; ++i)
    t[ty + 8 * i][tx] = w[(size_t)(k0 + ty + 8 * i) * 1536 + n0 + tx];
  __syncthreads();
  #pragma unroll
  for (int i = 0; i < 4; ++i)
    wt[(size_t)(n0 + ty + 8 * i) * 512 + k0 + tx] = f2bf(t[tx][ty + 8 * i]);
}

// ---- prep: depths, level buckets, slots, parent slots (1 block, 128 thr) ----
__global__ void prep_sched(const int* __restrict__ td_pidx,
                           const float* __restrict__ td_pval,
                           int* __restrict__ sched, int* __restrict__ meta,
                           int* __restrict__ gidx, int* __restrict__ pslot) {
  __shared__ unsigned char dep[NB][NL];
  __shared__ int cnt[256], cur[256], off[257];
  __shared__ int dmax;
  const int b = threadIdx.x;
  for (int d = b; d < 256; d += NB) { cnt[d] = 0; cur[d] = 0; }
  if (b == 0) dmax = 0;
  __syncthreads();
  int lmax = 0;
  for (int i = 0; i < NL; ++i) {
    float pv = td_pval[i * NB + b];
    int pi = td_pidx[i * NB + b];
    int d = (pv != 0.f) ? (int)dep[b][pi] + 1 : 0;   // head[i] < i
    dep[b][i] = (unsigned char)d;
    atomicAdd(&cnt[d], 1);
    lmax = max(lmax, d);
  }
  atomicMax(&dmax, lmax);
  __syncthreads();
  if (b == 0) {
    int s = 0;
    for (int d = 0; d < 256; ++d) { off[d] = s; s += cnt[d]; }
    off[256] = s;
  }
  __syncthreads();
  for (int i = 0; i < NL; ++i) {
    float pv = td_pval[i * NB + b];
    int pi = td_pidx[i * NB + b];
    int d = dep[b][i];
    int g = off[d] + atomicAdd(&cur[d], 1);
    sched[g] = (b << 8) | i;
    gidx[b * NL + i] = g;
    pslot[g] = (pv != 0.f) ? gidx[b * NL + pi] : -1;  // pi < i: already set
  }
  if (b == 0) meta[0] = dmax;
  for (int d = b; d < 256; d += NB) { meta[1 + d] = off[d]; meta[257 + d] = cnt[d]; }
}

// ---- prep: gather emb rows into slot order, f32 -> bf16 ----
__global__ void prep_xc(const float* __restrict__ emb, const int* __restrict__ sched,
                        unsigned short* __restrict__ Xc) {
  int g = blockIdx.x * 4 + (threadIdx.x >> 6);
  int lane = threadIdx.x & 63;
  int e = sched[g];
  int b = e >> 8, node = e & 255;
  const float* src = emb + ((size_t)node * NB + b) * 512 + lane * 8;
  f32x4 v0 = *(const f32x4*)src;
  f32x4 v1 = *(const f32x4*)(src + 4);
  *(short8*)(Xc + (size_t)g * 512 + lane * 8) = pk_bf16(v0, v1);
}

// ---- main persistent cooperative kernel ----
// 256 blocks x 256 thr: pass(2) x replica(4) x colgroup(32 x 16 h-cols).
// Wave slot = rep*4+wave (16 slots per (pass,cg)); tile = 32 rows x 16 cols.
__launch_bounds__(256, 1)
__global__ void tree_gru(const float* __restrict__ dt_b,
                         const float* __restrict__ td_b,
                         const unsigned short* __restrict__ wt,
                         const unsigned short* __restrict__ Xc,
                         unsigned short* __restrict__ Hdt,
                         unsigned short* __restrict__ Htd,
                         const int* __restrict__ sched,
                         const int* __restrict__ meta,
                         const int* __restrict__ pslot,
                         const int* __restrict__ root_index,
                         float* __restrict__ out) {
  extern __shared__ unsigned char lds[];
  const int tid = threadIdx.x;
  const int bi  = blockIdx.x;
  const int pass = bi >> 7;          // 0 = DT bottom-up, 1 = TD top-down
  const int rep  = (bi >> 5) & 3;
  const int cg   = bi & 31;
  const int w  = tid >> 6, l = tid & 63;
  const int lm = l & 15, kg = l >> 4;
  const int col = cg * 16 + lm;
  const int slot = rep * 4 + w;

  // stage weight slices: [mat(Wx,Uh)][gate(r,z,n)][n16][k512] bf16, XOR-swizzled
  for (int idx = tid; idx < 6144; idx += 256) {
    int k8  = idx & 63;
    int n   = (idx >> 6) & 15;
    int g   = (idx >> 10) % 3;
    int mat = idx / 3072;
    const unsigned short* src = wt + (size_t)(pass * 2 + mat) * (1536 * 512)
                                   + (size_t)(g * 512 + cg * 16 + n) * 512 + k8 * 8;
    short8 v = *(const short8*)src;
    int off = ((mat * 3 + g) * 16 + n) * 1024 + ((k8 * 16) ^ ((n & 7) << 4));
    *(short8*)(lds + off) = v;
  }
  __syncthreads();

  const float* bias = pass ? td_b : dt_b;
  const float br = bias[col], bz = bias[NH + col], bn = bias[2 * NH + col];
  const int swz = (lm & 7) << 4;
  const int base_wr = (0 * 16 + lm) * 1024;
  const int base_wz = (1 * 16 + lm) * 1024;
  const int base_wn = (2 * 16 + lm) * 1024;
  const int base_ur = (3 * 16 + lm) * 1024;
  const int base_uz = (4 * 16 + lm) * 1024;
  const int base_un = (5 * 16 + lm) * 1024;

  cooperative_groups::grid_group grid = cooperative_groups::this_grid();
  const int Dmax = meta[0];

  for (int p = 0; p <= Dmax; ++p) {
    const int d = pass ? p : (Dmax - p);
    const int off_d = meta[1 + d];
    const int cnt_d = meta[257 + d];
    const int T = (cnt_d + 31) >> 5;
    for (int t = slot; t < T; t += 16) {
      const int g0 = off_d + t * 32;
      const int rows = min(32, cnt_d - t * 32);
      const int gA0 = g0 + min(lm, rows - 1);
      const int gA1 = g0 + min(16 + lm, rows - 1);
      const unsigned short* x0p = Xc + (size_t)gA0 * 512;
      const unsigned short* x1p = Xc + (size_t)gA1 * 512;
      const unsigned short *h0p, *h1p;
      int hv0, hv1;
      if (pass == 0) {
        h0p = Hdt + (size_t)gA0 * 512; hv0 = 1;
        h1p = Hdt + (size_t)gA1 * 512; hv1 = 1;
      } else {
        int ps0 = pslot[gA0], ps1 = pslot[gA1];
        hv0 = ps0 >= 0; hv1 = ps1 >= 0;
        h0p = Htd + (size_t)max(ps0, 0) * 512;
        h1p = Htd + (size_t)max(ps1, 0) * 512;
      }
      f32x4 aR0={0,0,0,0}, aZ0={0,0,0,0}, aXN0={0,0,0,0}, aHN0={0,0,0,0};
      f32x4 aR1={0,0,0,0}, aZ1={0,0,0,0}, aXN1={0,0,0,0}, aHN1={0,0,0,0};
      const short8 zero8 = {0,0,0,0,0,0,0,0};
      #pragma unroll 4
      for (int kk = 0; kk < 16; ++kk) {
        const int ke = kk * 32 + kg * 8;
        const int kb = (kk * 64 + kg * 16) ^ swz;
        short8 ax0 = *(const short8*)(x0p + ke);
        short8 ax1 = *(const short8*)(x1p + ke);
        short8 th0 = *(const short8*)(h0p + ke);
        short8 th1 = *(const short8*)(h1p + ke);
        short8 ah0 = hv0 ? th0 : zero8;
        short8 ah1 = hv1 ? th1 : zero8;
        short8 bwr = *(const short8*)(lds + base_wr + kb);
        short8 bwz = *(const short8*)(lds + base_wz + kb);
        short8 bwn = *(const short8*)(lds + base_wn + kb);
        short8 bur = *(const short8*)(lds + base_ur + kb);
        short8 buz = *(const short8*)(lds + base_uz + kb);
        short8 bun = *(const short8*)(lds + base_un + kb);
        aR0  = __builtin_amdgcn_mfma_f32_16x16x32_bf16(ax0, bwr, aR0, 0, 0, 0);
        aR1  = __builtin_amdgcn_mfma_f32_16x16x32_bf16(ax1, bwr, aR1, 0, 0, 0);
        aZ0  = __builtin_amdgcn_mfma_f32_16x16x32_bf16(ax0, bwz, aZ0, 0, 0, 0);
        aZ1  = __builtin_amdgcn_mfma_f32_16x16x32_bf16(ax1, bwz, aZ1, 0, 0, 0);
        aXN0 = __builtin_amdgcn_mfma_f32_16x16x32_bf16(ax0, bwn, aXN0, 0, 0, 0);
        aXN1 = __builtin_amdgcn_mfma_f32_16x16x32_bf16(ax1, bwn, aXN1, 0, 0, 0);
        aR0  = __builtin_amdgcn_mfma_f32_16x16x32_bf16(ah0, bur, aR0, 0, 0, 0);
        aR1  = __builtin_amdgcn_mfma_f32_16x16x32_bf16(ah1, bur, aR1, 0, 0, 0);
        aZ0  = __builtin_amdgcn_mfma_f32_16x16x32_bf16(ah0, buz, aZ0, 0, 0, 0);
        aZ1  = __builtin_amdgcn_mfma_f32_16x16x32_bf16(ah1, buz, aZ1, 0, 0, 0);
        aHN0 = __builtin_amdgcn_mfma_f32_16x16x32_bf16(ah0, bun, aHN0, 0, 0, 0);
        aHN1 = __builtin_amdgcn_mfma_f32_16x16x32_bf16(ah1, bun, aHN1, 0, 0, 0);
      }
      // epilogue: frag f covers rows f*16 + kg*4 + q, col = lm
      #pragma unroll
      for (int fq = 0; fq < 8; ++fq) {
        const int f = fq >> 2, q = fq & 3;
        const int r = f * 16 + kg * 4 + q;
        if (r >= rows) continue;
        const int g = g0 + r;
        const float vR  = f ? aR1[q]  : aR0[q];
        const float vZ  = f ? aZ1[q]  : aZ0[q];
        const float vXN = f ? aXN1[q] : aXN0[q];
        const float vHN = f ? aHN1[q] : aHN0[q];
        const int e = sched[g];
        const int bO = e >> 8, node = e & 255;
        const int ps = pslot[g];
        float hprev;
        if (pass == 0) hprev = bf2f(Hdt[(size_t)g * 512 + col]);
        else           hprev = (ps >= 0) ? bf2f(Htd[(size_t)ps * 512 + col]) : 0.f;
        float rr = 1.f / (1.f + __expf(-(vR + br)));
        float zz = 1.f / (1.f + __expf(-(vZ + bz)));
        float e2 = __expf(2.f * (vXN + bn + rr * vHN));
        float nn = (e2 - 1.f) / (e2 + 1.f);             // tanh
        float h = (1.f - zz) * nn + zz * hprev;
        out[((size_t)bO * NL + node) * 1024 + pass * 512 + col] = h;
        // paired bf16x2 update (lanes lm, lm^1 share row g)
        float ho = __shfl_xor(h, 1);
        if ((lm & 1) == 0) {
          unsigned int ud;
          asm("v_cvt_pk_bf16_f32 %0, %1, %2" : "=v"(ud) : "v"(h), "v"(ho));
          if (pass == 0) {
            if (ps >= 0) atom_pk_bf16(Hdt + (size_t)ps * 512 + col, ud);
          } else {
            *(unsigned int*)(Htd + (size_t)g * 512 + col) = ud;
          }
        }
      }
    }
    grid.sync();
  }

  // output_t: root hidden concat
  if (bi < NB) {
    int b = bi, root = root_index[b];
    for (int c = tid; c < 1024; c += 256)
      out[(size_t)NB * NL * 1024 + (size_t)b * 1024 + c] =
          out[((size_t)b * NL + root) * 1024 + c];
  }
}

extern "C" void kernel_launch(void* const* d_in, const int* in_sizes, int n_in,
                              void* d_out, int out_size, void* d_ws, size_t ws_size,
                              hipStream_t stream) {
  (void)in_sizes; (void)n_in; (void)out_size; (void)ws_size;
  const float* emb      = (const float*)d_in[0];
  const int*   td_pidx  = (const int*)d_in[4];
  const float* td_pval  = (const float*)d_in[5];
  const int*   root_idx = (const int*)d_in[6];
  const float* dt_Wx    = (const float*)d_in[7];
  const float* dt_Uh    = (const float*)d_in[8];
  const float* dt_b     = (const float*)d_in[9];
  const float* td_Wx    = (const float*)d_in[10];
  const float* td_Uh    = (const float*)d_in[11];
  const float* td_b     = (const float*)d_in[12];
  float* out = (float*)d_out;

  unsigned short* wt  = (unsigned short*)d_ws;
  unsigned short* Xc  = wt + (size_t)4 * 1536 * 512;
  unsigned short* Hdt = Xc + (size_t)NG * NH;
  unsigned short* Htd = Hdt + (size_t)NG * NH;
  int* sched = (int*)(Htd + (size_t)NG * NH);
  int* meta  = sched + NG;
  int* gidx  = meta + 513;
  int* pslot = gidx + NG;

  (void)hipMemsetAsync(Hdt, 0, (size_t)NG * NH * 2, stream);
  dim3 tg(48, 16);
  prep_wt<<<tg, dim3(256), 0, stream>>>(dt_Wx, wt);
  prep_wt<<<tg, dim3(256), 0, stream>>>(dt_Uh, wt + (size_t)1536 * 512);
  prep_wt<<<tg, dim3(256), 0, stream>>>(td_Wx, wt + (size_t)2 * 1536 * 512);
  prep_wt<<<tg, dim3(256), 0, stream>>>(td_Uh, wt + (size_t)3 * 1536 * 512);
  prep_sched<<<dim3(1), dim3(NB), 0, stream>>>(td_pidx, td_pval, sched, meta, gidx, pslot);
  prep_xc<<<dim3(NG / 4), dim3(256), 0, stream>>>(emb, sched, Xc);

  (void)hipFuncSetAttribute((const void*)tree_gru,
                            hipFuncAttributeMaxDynamicSharedMemorySize, 98304);

  void* args[] = {
    (void*)&dt_b, (void*)&td_b, (void*)&wt, (void*)&Xc, (void*)&Hdt, (void*)&Htd,
    (void*)&sched, (void*)&meta, (void*)&pslot, (void*)&root_idx, (void*)&out
  };
  (void)hipLaunchCooperativeKernel((const void*)tree_gru, dim3(256), dim3(256),
                                   args, 98304u, stream);
}

// Round 4
// 1826.520 us; speedup vs baseline: 3.3893x; 1.1662x over previous
//
#include <hip/hip_runtime.h>
#include <hip/hip_cooperative_groups.h>

// Tree-GRU encoder, level-scheduled, compact bf16 state.
// Round-4 changes vs round-3:
//  - 512-thread blocks (8 waves/CU = 2/SIMD) for latency hiding; VGPR cap 256.
//  - depth-4 software prefetch of A-operands (16 outstanding loads/wave).
//  - zero-row pointer instead of per-kstep cndmask for TD roots.
//  - prep_sched atomics-free (LDS per-tree counts + parallel prefix) — the
//    round-3 version burned ~350us on same-address LDS atomic contention.
//
// ws layout (~107 MB):
//   wt    bf16 4x[1536][512]   6,291,456 B
//   Xc    bf16 [32768][512]   33,554,432 B
//   Hdt   bf16 [32768][512]   33,554,432 B   (memset 0 each call, + zrow)
//   zrow  bf16 [512]                1,024 B   (stays 0)
//   Htd   bf16 [32768][512]   33,554,432 B
//   sched i32 [32768], meta i32 [513], gidx i32 [32768], pslot i32 [32768]

#define NL 256
#define NB 128
#define NH 512
#define NG (NB * NL)

typedef short short8 __attribute__((ext_vector_type(8)));
typedef float f32x4 __attribute__((ext_vector_type(4)));

__device__ __forceinline__ float bf2f(unsigned short u) {
  union { unsigned int i; float f; } c; c.i = ((unsigned int)u) << 16; return c.f;
}
__device__ __forceinline__ unsigned short f2bf(float f) {
  union { float f; unsigned int i; } c; c.f = f;
  return (unsigned short)((c.i + 0x7FFFu + ((c.i >> 16) & 1u)) >> 16);  // RNE
}
__device__ __forceinline__ short8 pk_bf16(f32x4 a, f32x4 b) {
  union { unsigned int u[4]; short8 s; } r;
  asm("v_cvt_pk_bf16_f32 %0, %1, %2" : "=v"(r.u[0]) : "v"(a[0]), "v"(a[1]));
  asm("v_cvt_pk_bf16_f32 %0, %1, %2" : "=v"(r.u[1]) : "v"(a[2]), "v"(a[3]));
  asm("v_cvt_pk_bf16_f32 %0, %1, %2" : "=v"(r.u[2]) : "v"(b[0]), "v"(b[1]));
  asm("v_cvt_pk_bf16_f32 %0, %1, %2" : "=v"(r.u[3]) : "v"(b[2]), "v"(b[3]));
  return r.s;
}
__device__ __forceinline__ void atom_pk_bf16(unsigned short* p, unsigned int ud) {
  asm volatile("global_atomic_pk_add_bf16 %0, %1, off" :: "v"((void*)p), "v"(ud) : "memory");
}

// ---- prep: 4 weight matrices [512][1536] f32 -> transposed [1536][512] bf16 ----
__global__ void prep_wt4(const float* __restrict__ w0, const float* __restrict__ w1,
                         const float* __restrict__ w2, const float* __restrict__ w3,
                         unsigned short* __restrict__ wt) {
  __shared__ float t[32][33];
  const float* w = blockIdx.z == 0 ? w0 : blockIdx.z == 1 ? w1 : blockIdx.z == 2 ? w2 : w3;
  unsigned short* dst = wt + (size_t)blockIdx.z * 1536 * 512;
  int n0 = blockIdx.x * 32, k0 = blockIdx.y * 32;
  int tx = threadIdx.x & 31, ty = threadIdx.x >> 5;
  #pragma unroll
  for (int i = 0; i < 4; ++i)
    t[ty + 8 * i][tx] = w[(size_t)(k0 + ty + 8 * i) * 1536 + n0 + tx];
  __syncthreads();
  #pragma unroll
  for (int i = 0; i < 4; ++i)
    dst[(size_t)(n0 + ty + 8 * i) * 512 + k0 + tx] = f2bf(t[tx][ty + 8 * i]);
}

// ---- prep: depths, level buckets, slots, parent slots (1 block, 256 thr, no atomics) ----
__global__ void prep_sched(const int* __restrict__ td_pidx,
                           const float* __restrict__ td_pval,
                           int* __restrict__ sched, int* __restrict__ meta,
                           int* __restrict__ gidx, int* __restrict__ pslot) {
  __shared__ unsigned char dep[NB][NL];       // 32 KB
  __shared__ unsigned short cnb[NB][256];     // 64 KB: counts -> start offsets
  __shared__ int cnt[256];
  __shared__ int off[257];
  __shared__ int dmax_s;
  const int tid = threadIdx.x;
  for (int j = tid; j < NB * 256; j += 256) ((unsigned short*)cnb)[j] = 0;
  if (tid == 0) dmax_s = 0;
  __syncthreads();
  if (tid < NB) {
    int b = tid, lmax = 0;
    for (int i = 0; i < NL; ++i) {
      float pv = td_pval[i * NB + b];
      int pi = td_pidx[i * NB + b];
      int d = (pv != 0.f) ? (int)dep[b][pi] + 1 : 0;   // head[i] < i
      dep[b][i] = (unsigned char)d;
      cnb[b][d]++;
      lmax = max(lmax, d);
    }
    atomicMax(&dmax_s, lmax);   // 128 total, negligible
  }
  __syncthreads();
  { // column sums per depth (d = tid)
    int s = 0;
    for (int b = 0; b < NB; ++b) s += cnb[b][tid];
    cnt[tid] = s;
  }
  __syncthreads();
  if (tid == 0) {
    int s = 0;
    for (int d = 0; d < 256; ++d) { off[d] = s; s += cnt[d]; }
    off[256] = s;
  }
  __syncthreads();
  { // per-(b,d) start offsets (d = tid)
    int run = off[tid];
    for (int b = 0; b < NB; ++b) {
      int t = cnb[b][tid];
      cnb[b][tid] = (unsigned short)run;
      run += t;
    }
  }
  __syncthreads();
  if (tid < NB) {
    int b = tid;
    for (int i = 0; i < NL; ++i) {
      float pv = td_pval[i * NB + b];
      int pi = td_pidx[i * NB + b];
      int d = dep[b][i];
      int g = cnb[b][d]++;
      sched[g] = (b << 8) | i;
      gidx[b * NL + i] = g;
      pslot[g] = (pv != 0.f) ? gidx[b * NL + pi] : -1;   // pi < i: already set
    }
  }
  if (tid == 0) meta[0] = dmax_s;
  __syncthreads();
  meta[1 + tid] = off[tid];
  meta[257 + tid] = cnt[tid];
}

// ---- prep: gather emb rows into slot order, f32 -> bf16 ----
__global__ void prep_xc(const float* __restrict__ emb, const int* __restrict__ sched,
                        unsigned short* __restrict__ Xc) {
  int g = blockIdx.x * 4 + (threadIdx.x >> 6);
  int lane = threadIdx.x & 63;
  int e = sched[g];
  int b = e >> 8, node = e & 255;
  const float* src = emb + ((size_t)node * NB + b) * 512 + lane * 8;
  f32x4 v0 = *(const f32x4*)src;
  f32x4 v1 = *(const f32x4*)(src + 4);
  *(short8*)(Xc + (size_t)g * 512 + lane * 8) = pk_bf16(v0, v1);
}

// ---- main persistent cooperative kernel ----
// 256 blocks x 512 thr (8 waves): pass(2) x replica(4) x colgroup(32 x 16 cols).
// slot = rep*8 + wave (32 slots per (pass,cg)); tile = 32 rows x 16 cols.
__launch_bounds__(512, 2)
__global__ void tree_gru(const float* __restrict__ dt_b,
                         const float* __restrict__ td_b,
                         const unsigned short* __restrict__ wt,
                         const unsigned short* __restrict__ Xc,
                         unsigned short* __restrict__ Hdt,
                         unsigned short* __restrict__ Htd,
                         const unsigned short* __restrict__ zrow,
                         const int* __restrict__ sched,
                         const int* __restrict__ meta,
                         const int* __restrict__ pslot,
                         const int* __restrict__ root_index,
                         float* __restrict__ out) {
  extern __shared__ unsigned char lds[];
  const int tid = threadIdx.x;
  const int bi  = blockIdx.x;
  const int pass = bi >> 7;          // 0 = DT bottom-up, 1 = TD top-down
  const int rep  = (bi >> 5) & 3;
  const int cg   = bi & 31;
  const int w  = tid >> 6, l = tid & 63;
  const int lm = l & 15, kg = l >> 4;
  const int col = cg * 16 + lm;
  const int slot = rep * 8 + w;      // 0..31

  // stage weight slices: [mat(Wx,Uh)][gate(r,z,n)][n16][k512] bf16, XOR-swizzled
  for (int idx = tid; idx < 6144; idx += 512) {
    int k8  = idx & 63;
    int n   = (idx >> 6) & 15;
    int g   = (idx >> 10) % 3;
    int mat = idx / 3072;
    const unsigned short* src = wt + (size_t)(pass * 2 + mat) * (1536 * 512)
                                   + (size_t)(g * 512 + cg * 16 + n) * 512 + k8 * 8;
    short8 v = *(const short8*)src;
    int off = ((mat * 3 + g) * 16 + n) * 1024 + ((k8 * 16) ^ ((n & 7) << 4));
    *(short8*)(lds + off) = v;
  }
  __syncthreads();

  const float* bias = pass ? td_b : dt_b;
  const float br = bias[col], bz = bias[NH + col], bn = bias[2 * NH + col];
  const int swz = (lm & 7) << 4;
  const int base_wr = (0 * 16 + lm) * 1024;
  const int base_wz = (1 * 16 + lm) * 1024;
  const int base_wn = (2 * 16 + lm) * 1024;
  const int base_ur = (3 * 16 + lm) * 1024;
  const int base_uz = (4 * 16 + lm) * 1024;
  const int base_un = (5 * 16 + lm) * 1024;

  cooperative_groups::grid_group grid = cooperative_groups::this_grid();
  const int Dmax = meta[0];

  for (int p = 0; p <= Dmax; ++p) {
    const int d = pass ? p : (Dmax - p);
    const int off_d = meta[1 + d];
    const int cnt_d = meta[257 + d];
    const int T = (cnt_d + 31) >> 5;
    for (int t = slot; t < T; t += 32) {
      const int g0 = off_d + t * 32;
      const int rows = min(32, cnt_d - t * 32);
      const int gA0 = g0 + min(lm, rows - 1);
      const int gA1 = g0 + min(16 + lm, rows - 1);
      const unsigned short* x0p = Xc + (size_t)gA0 * 512;
      const unsigned short* x1p = Xc + (size_t)gA1 * 512;
      const unsigned short *h0p, *h1p;
      if (pass == 0) {
        h0p = Hdt + (size_t)gA0 * 512;
        h1p = Hdt + (size_t)gA1 * 512;
      } else {
        int ps0 = pslot[gA0], ps1 = pslot[gA1];
        h0p = (ps0 >= 0) ? Htd + (size_t)ps0 * 512 : zrow;   // root -> zero row
        h1p = (ps1 >= 0) ? Htd + (size_t)ps1 * 512 : zrow;
      }
      f32x4 aR0={0,0,0,0}, aZ0={0,0,0,0}, aXN0={0,0,0,0}, aHN0={0,0,0,0};
      f32x4 aR1={0,0,0,0}, aZ1={0,0,0,0}, aXN1={0,0,0,0}, aHN1={0,0,0,0};
      // depth-4 prefetch pipeline over 16 k-steps (fully unrolled, static idx)
      short8 bx0[4], bx1[4], bh0[4], bh1[4];
      #pragma unroll
      for (int j = 0; j < 4; ++j) {
        const int ke = j * 32 + kg * 8;
        bx0[j] = *(const short8*)(x0p + ke);
        bx1[j] = *(const short8*)(x1p + ke);
        bh0[j] = *(const short8*)(h0p + ke);
        bh1[j] = *(const short8*)(h1p + ke);
      }
      #pragma unroll
      for (int kk = 0; kk < 16; ++kk) {
        const int jb = kk & 3;
        const short8 ax0 = bx0[jb], ax1 = bx1[jb];
        const short8 ah0 = bh0[jb], ah1 = bh1[jb];
        if (kk < 12) {
          const int ke = (kk + 4) * 32 + kg * 8;
          bx0[jb] = *(const short8*)(x0p + ke);
          bx1[jb] = *(const short8*)(x1p + ke);
          bh0[jb] = *(const short8*)(h0p + ke);
          bh1[jb] = *(const short8*)(h1p + ke);
        }
        const int kb = (kk * 64 + kg * 16) ^ swz;
        short8 bwr = *(const short8*)(lds + base_wr + kb);
        short8 bwz = *(const short8*)(lds + base_wz + kb);
        short8 bwn = *(const short8*)(lds + base_wn + kb);
        short8 bur = *(const short8*)(lds + base_ur + kb);
        short8 buz = *(const short8*)(lds + base_uz + kb);
        short8 bun = *(const short8*)(lds + base_un + kb);
        aR0  = __builtin_amdgcn_mfma_f32_16x16x32_bf16(ax0, bwr, aR0, 0, 0, 0);
        aR1  = __builtin_amdgcn_mfma_f32_16x16x32_bf16(ax1, bwr, aR1, 0, 0, 0);
        aZ0  = __builtin_amdgcn_mfma_f32_16x16x32_bf16(ax0, bwz, aZ0, 0, 0, 0);
        aZ1  = __builtin_amdgcn_mfma_f32_16x16x32_bf16(ax1, bwz, aZ1, 0, 0, 0);
        aXN0 = __builtin_amdgcn_mfma_f32_16x16x32_bf16(ax0, bwn, aXN0, 0, 0, 0);
        aXN1 = __builtin_amdgcn_mfma_f32_16x16x32_bf16(ax1, bwn, aXN1, 0, 0, 0);
        aR0  = __builtin_amdgcn_mfma_f32_16x16x32_bf16(ah0, bur, aR0, 0, 0, 0);
        aR1  = __builtin_amdgcn_mfma_f32_16x16x32_bf16(ah1, bur, aR1, 0, 0, 0);
        aZ0  = __builtin_amdgcn_mfma_f32_16x16x32_bf16(ah0, buz, aZ0, 0, 0, 0);
        aZ1  = __builtin_amdgcn_mfma_f32_16x16x32_bf16(ah1, buz, aZ1, 0, 0, 0);
        aHN0 = __builtin_amdgcn_mfma_f32_16x16x32_bf16(ah0, bun, aHN0, 0, 0, 0);
        aHN1 = __builtin_amdgcn_mfma_f32_16x16x32_bf16(ah1, bun, aHN1, 0, 0, 0);
      }
      // epilogue: frag f covers rows f*16 + kg*4 + q, col = lm
      #pragma unroll
      for (int fq = 0; fq < 8; ++fq) {
        const int f = fq >> 2, q = fq & 3;
        const int r = f * 16 + kg * 4 + q;
        if (r >= rows) continue;
        const int g = g0 + r;
        const float vR  = f ? aR1[q]  : aR0[q];
        const float vZ  = f ? aZ1[q]  : aZ0[q];
        const float vXN = f ? aXN1[q] : aXN0[q];
        const float vHN = f ? aHN1[q] : aHN0[q];
        const int e = sched[g];
        const int bO = e >> 8, node = e & 255;
        const int ps = pslot[g];
        float hprev;
        if (pass == 0) hprev = bf2f(Hdt[(size_t)g * 512 + col]);
        else           hprev = (ps >= 0) ? bf2f(Htd[(size_t)ps * 512 + col]) : 0.f;
        float rr = 1.f / (1.f + __expf(-(vR + br)));
        float zz = 1.f / (1.f + __expf(-(vZ + bz)));
        float e2 = __expf(2.f * (vXN + bn + rr * vHN));
        float nn = (e2 - 1.f) / (e2 + 1.f);             // tanh
        float h = (1.f - zz) * nn + zz * hprev;
        out[((size_t)bO * NL + node) * 1024 + pass * 512 + col] = h;
        // paired bf16x2 update (lanes lm, lm^1 share row g)
        float ho = __shfl_xor(h, 1);
        if ((lm & 1) == 0) {
          unsigned int ud;
          asm("v_cvt_pk_bf16_f32 %0, %1, %2" : "=v"(ud) : "v"(h), "v"(ho));
          if (pass == 0) {
            if (ps >= 0) atom_pk_bf16(Hdt + (size_t)ps * 512 + col, ud);
          } else {
            *(unsigned int*)(Htd + (size_t)g * 512 + col) = ud;
          }
        }
      }
    }
    grid.sync();
  }

  // output_t: root hidden concat
  if (bi < NB) {
    int b = bi, root = root_index[b];
    for (int c = tid; c < 1024; c += 512)
      out[(size_t)NB * NL * 1024 + (size_t)b * 1024 + c] =
          out[((size_t)b * NL + root) * 1024 + c];
  }
}

extern "C" void kernel_launch(void* const* d_in, const int* in_sizes, int n_in,
                              void* d_out, int out_size, void* d_ws, size_t ws_size,
                              hipStream_t stream) {
  (void)in_sizes; (void)n_in; (void)out_size; (void)ws_size;
  const float* emb      = (const float*)d_in[0];
  const int*   td_pidx  = (const int*)d_in[4];
  const float* td_pval  = (const float*)d_in[5];
  const int*   root_idx = (const int*)d_in[6];
  const float* dt_Wx    = (const float*)d_in[7];
  const float* dt_Uh    = (const float*)d_in[8];
  const float* dt_b     = (const float*)d_in[9];
  const float* td_Wx    = (const float*)d_in[10];
  const float* td_Uh    = (const float*)d_in[11];
  const float* td_b     = (const float*)d_in[12];
  float* out = (float*)d_out;

  unsigned short* wt   = (unsigned short*)d_ws;
  unsigned short* Xc   = wt + (size_t)4 * 1536 * 512;
  unsigned short* Hdt  = Xc + (size_t)NG * NH;
  unsigned short* zrow = Hdt + (size_t)NG * NH;
  unsigned short* Htd  = zrow + NH;
  int* sched = (int*)(Htd + (size_t)NG * NH);
  int* meta  = sched + NG;
  int* gidx  = meta + 513;
  int* pslot = gidx + NG;

  (void)hipMemsetAsync(Hdt, 0, ((size_t)NG * NH + NH) * 2, stream);  // Hdt + zrow
  prep_wt4<<<dim3(48, 16, 4), dim3(256), 0, stream>>>(dt_Wx, dt_Uh, td_Wx, td_Uh, wt);
  prep_sched<<<dim3(1), dim3(256), 0, stream>>>(td_pidx, td_pval, sched, meta, gidx, pslot);
  prep_xc<<<dim3(NG / 4), dim3(256), 0, stream>>>(emb, sched, Xc);

  (void)hipFuncSetAttribute((const void*)tree_gru,
                            hipFuncAttributeMaxDynamicSharedMemorySize, 98304);

  void* args[] = {
    (void*)&dt_b, (void*)&td_b, (void*)&wt, (void*)&Xc, (void*)&Hdt, (void*)&Htd,
    (void*)&zrow, (void*)&sched, (void*)&meta, (void*)&pslot, (void*)&root_idx, (void*)&out
  };
  (void)hipLaunchCooperativeKernel((const void*)tree_gru, dim3(256), dim3(512),
                                   args, 98304u, stream);
}